// Round 18
// baseline (863.974 us; speedup 1.0000x reference)
//
#include <hip/hip_runtime.h>

#define E 1024
#define H 4096
#define NLAYER 24
#define V 50277
#define NB 256
#define NT 1024
#define LN_EPS 1e-5f

typedef unsigned long long u64;

// ---- LDS float offsets (dynamic shared, 155904 B) ----
// R1 (16 slots x 1024): slots 0-11: A(l) -> fkw(l) rows 0-11 -> A(l+1)
//                       slots 12-15: fkw(l) rows 12-15 (DMA by waves 0-3)
// R2 (16 slots x 1024): fvw(l) chunk c in slot c (waves 8-11 fill 12-15 too)
#define R1O    0
#define R2O    16384
#define POOLO  32768   // 4096: xk|xv|xr|wkv (A/B); fxk|fxr (C); fk (D)
#define SXO    36864   // 1024
#define SSXO   37888   // 1024
#define REDO   38912   // 32
#define PARTO  38944   // 16
#define PART2O 38960   // 16
#define SMEMF  38976

struct Params {
  const float* emb;   const float* ln0_w; const float* ln0_b;
  const float* ln1_w; const float* ln1_b;
  const float* tmk;   const float* tmv;   const float* tmr;
  const float* tf;    const float* td;
  const float* kw;    const float* vw;    const float* rw;  const float* ow;
  const float* ln2_w; const float* ln2_b;
  const float* ftmk;  const float* ftmr;
  const float* fkw;   const float* fvw;   const float* frw;
  const float* lnow;  const float* lnob;  const float* headw;
  const float* st;    const int* tok;
  float* out; float* ws;
};

// ---- tagged 8-byte dataflow handoff (relaxed agent scope) ----
__device__ __forceinline__ void stg_tag(u64* p, float v, unsigned tag) {
  u64 w = ((u64)__float_as_uint(v) << 32) | (u64)tag;
  __hip_atomic_store(p, w, __ATOMIC_RELAXED, __HIP_MEMORY_SCOPE_AGENT);
}
__device__ __forceinline__ u64 ld_tag(const u64* p) {
  return __hip_atomic_load(p, __ATOMIC_RELAXED, __HIP_MEMORY_SCOPE_AGENT);
}
#define TAGWAIT(w, ptr, tagv) \
  while ((unsigned)(w) != (tagv)) { __builtin_amdgcn_s_sleep(1); (w) = ld_tag(ptr); }
__device__ __forceinline__ float tagval(u64 w) {
  return __uint_as_float((unsigned)(w >> 32));
}

// counted vmem wait (T4): N = number of vmem instrs issued after the data
// we need; in-order retirement makes smaller N strictly stronger.
#define WAITVM(N) asm volatile("s_waitcnt vmcnt(" #N ")" ::: "memory")

// lgkm-only barrier (T3): does NOT drain vmcnt -> DMA stays in flight.
__device__ __forceinline__ void bar() {
  asm volatile("s_waitcnt lgkmcnt(0)" ::: "memory");
  __builtin_amdgcn_s_barrier();
  asm volatile("" ::: "memory");
}

// zero-VGPR global->LDS DMA: 64 lanes x 16 B = 1 KB per call.
__device__ __forceinline__ void gload_lds16(const float* g, float* l) {
  __builtin_amdgcn_global_load_lds(
      (const __attribute__((address_space(1))) unsigned int*)(g),
      (__attribute__((address_space(3))) unsigned int*)(l), 16, 0, 0);
}
__device__ __forceinline__ void pf_row4k(const float* row, float* dst, int lane) {
#pragma unroll
  for (int c = 0; c < 4; ++c)
    gload_lds16(row + c * 256 + lane * 4, dst + c * 256);
}

__device__ __forceinline__ float warp_sum(float v) {
#pragma unroll
  for (int off = 32; off; off >>= 1) v += __shfl_down(v, off);
  return v;
}

__device__ __forceinline__ float dot4(float4 a, float4 b) {
  return a.x * b.x + a.y * b.y + a.z * b.z + a.w * b.w;
}

__device__ __forceinline__ float dotlds(const float* wrow, const float* vec, int lane) {
  const float4* w4 = (const float4*)wrow;
  const float4* v4 = (const float4*)vec;
  float acc = 0.f;
#pragma unroll
  for (int p = 0; p < 4; ++p)
    acc += dot4(w4[lane + p * 64], v4[lane + p * 64]);
  return warp_sum(acc);
}

// LN0 only: full-block stats with regular __syncthreads (one-time drain is ok)
__device__ __forceinline__ float2 ln_stats_w16(float v, float* red) {
  float a = v, b = v * v;
#pragma unroll
  for (int off = 32; off; off >>= 1) { a += __shfl_xor(a, off); b += __shfl_xor(b, off); }
  const int wid = threadIdx.x >> 6, lane = threadIdx.x & 63;
  if (lane == 0) { red[2 * wid] = a; red[2 * wid + 1] = b; }
  __syncthreads();
  float s1 = 0.f, s2 = 0.f;
  const float2* r2 = (const float2*)red;
#pragma unroll
  for (int j = 0; j < 16; ++j) { float2 t = r2[j]; s1 += t.x; s2 += t.y; }
  float m = s1 * (1.f / E);
  return make_float2(m, s2 * (1.f / E) - m * m);
}

__global__ __launch_bounds__(NT, 1) void rwkv_kernel(Params p) {
  const int tid = threadIdx.x, bid = blockIdx.x;
  const int lane = tid & 63, wid = tid >> 6;

  extern __shared__ float smem[];
  float* r1     = smem + R1O;
  float* r2     = smem + R2O;
  float* pool   = smem + POOLO;
  float* s_x    = smem + SXO;
  float* s_sx   = smem + SSXO;
  float* s_red  = smem + REDO;
  float* s_part = smem + PARTO;
  float* s_part2= smem + PART2O;

  u64* tws = (u64*)p.ws;
  u64* tk  = tws;             // [2][E]
  u64* tv  = tws + 2 * E;
  u64* tr  = tws + 4 * E;
  u64* tsx = tws + 6 * E;
  u64* tx  = tws + 8 * E;
  u64* tfk = tws + 10 * E;    // [2][H]

  float* out_st = p.out + V;
  const int token = p.tok[0];

  const bool isPol = wid >= 12;        // poller waves: poll + elementwise, NO DMA
  const int pw = wid - 12;             // poller wave id 0-3
  const int pt = tid - 768;            // poller thread 0-255 (elems pt+256*i)

  // compute-wave (wid<12) mappings
  const int rA = bid * 12 + wid;                  // k/v/r row
  const int matA = rA >> 10, rmA = rA & (E - 1);
  float* wA = r1 + wid * 1024;

  // ---- init: A(0) DMA by compute waves ----
  if (!isPol) {
    const float* W = (matA == 0 ? p.kw : matA == 1 ? p.vw : p.rw) + (size_t)rmA * E;
    pf_row4k(W, wA, lane);
  }

  // LN0 (all threads; its __syncthreads drains init DMA once -- fine)
  {
    float v = p.emb[(size_t)token * E + tid];
    float2 mv = ln_stats_w16(v, s_red);
    s_x[tid] = (v - mv.x) / sqrtf(mv.y + LN_EPS) * p.ln0_w[tid] + p.ln0_b[tid];
  }
  __syncthreads();

  for (int l = 0; l < NLAYER; ++l) {
    const float* stl = p.st + (size_t)5 * l * E;
    float* ostl = out_st + (size_t)5 * l * E;
    const int par = l & 1;
    const unsigned tg = (unsigned)(l + 1);

    // ================ Phase A: poll x, LN1+mix (pollers); k/v/r dots ================
    float xv0, xv1, xv2, xv3;
    float a0[4], a1[4], a2[4], a3[4], a4[4], a5[4];
    if (isPol) {
#pragma unroll
      for (int i = 0; i < 4; ++i) { int e = pt + (i << 8);
        a0[i] = p.ln1_w[l * E + e]; a1[i] = p.ln1_b[l * E + e];
        a2[i] = stl[E + e];
        a3[i] = p.tmk[l * E + e]; a4[i] = p.tmv[l * E + e]; a5[i] = p.tmr[l * E + e];
      }
      if (l > 0) {
        const u64* b = tx + par * E;
        u64 q0 = ld_tag(b + pt), q1 = ld_tag(b + pt + 256);
        u64 q2 = ld_tag(b + pt + 512), q3 = ld_tag(b + pt + 768);
        TAGWAIT(q0, b + pt, (unsigned)l);       TAGWAIT(q1, b + pt + 256, (unsigned)l);
        TAGWAIT(q2, b + pt + 512, (unsigned)l); TAGWAIT(q3, b + pt + 768, (unsigned)l);
        xv0 = tagval(q0); xv1 = tagval(q1); xv2 = tagval(q2); xv3 = tagval(q3);
        s_x[pt] = xv0; s_x[pt + 256] = xv1; s_x[pt + 512] = xv2; s_x[pt + 768] = xv3;
      } else {
        xv0 = s_x[pt]; xv1 = s_x[pt + 256]; xv2 = s_x[pt + 512]; xv3 = s_x[pt + 768];
      }
      float sa = xv0 + xv1 + xv2 + xv3;
      float sb = xv0 * xv0 + xv1 * xv1 + xv2 * xv2 + xv3 * xv3;
#pragma unroll
      for (int off = 32; off; off >>= 1) { sa += __shfl_xor(sa, off); sb += __shfl_xor(sb, off); }
      if (lane == 0) { s_red[2 * pw] = sa; s_red[2 * pw + 1] = sb; }
    }
    bar(); // B1: stats partials visible
    if (isPol) {
      float s1 = s_red[0] + s_red[2] + s_red[4] + s_red[6];
      float s2 = s_red[1] + s_red[3] + s_red[5] + s_red[7];
      float m = s1 * (1.f / E), var = s2 * (1.f / E) - m * m;
      float is = 1.f / sqrtf(var + LN_EPS);
      float xvv[4] = { xv0, xv1, xv2, xv3 };
#pragma unroll
      for (int i = 0; i < 4; ++i) { int e = pt + (i << 8);
        float xn = (xvv[i] - m) * is * a0[i] + a1[i];
        pool[e]        = xn * a3[i] + a2[i] * (1.f - a3[i]);   // xk
        pool[1024 + e] = xn * a4[i] + a2[i] * (1.f - a4[i]);   // xv
        pool[2048 + e] = xn * a5[i] + a2[i] * (1.f - a5[i]);   // xr
        if (bid == 0) ostl[E + e] = xn;                        // new att_x
      }
    }
    bar(); // B2: mix ready
    if (!isPol) {
      WAITVM(0);   // A row resident (DMA'd >=1 phase ago)
      float d = dotlds(wA, pool + matA * 1024, lane);
      if (lane == 0) {
        u64* dst = (matA == 0 ? tk : matA == 1 ? tv : tr) + par * E + rmA;
        stg_tag(dst, matA == 2 ? 1.f / (1.f + expf(-d)) : d, tg);
      }
    }

    // ================ Phase B: WKV (pollers); ow dots ================
    float4 wow0, wow1;
    if (!isPol) {
      { int c = wid;
        wow0 = ((const float4*)(p.ow + (size_t)l * E * E +
                 (size_t)(bid * 4 + (c >> 2)) * E + (c & 3) * 256))[lane]; }
      if (wid < 4) { int c = 12 + wid;
        wow1 = ((const float4*)(p.ow + (size_t)l * E * E +
                 (size_t)(bid * 4 + (c >> 2)) * E + (c & 3) * 256))[lane]; }
      // fkw DMA (stays in flight across barriers; consumed in C via WAITVM)
      pf_row4k(p.fkw + (size_t)l * H * E + (size_t)(bid * 16 + wid) * E, wA, lane);
      if (wid < 4)
        pf_row4k(p.fkw + (size_t)l * H * E + (size_t)(bid * 16 + 12 + wid) * E,
                 r1 + (12 + wid) * 1024, lane);
    } else {
      float wa[4], wb[4], wp[4], wf[4], wd[4];
#pragma unroll
      for (int i = 0; i < 4; ++i) { int e = pt + (i << 8);
        wa[i] = stl[2 * E + e]; wb[i] = stl[3 * E + e]; wp[i] = stl[4 * E + e];
        wf[i] = p.tf[l * E + e]; wd[i] = p.td[l * E + e];
      }
#pragma unroll
      for (int i = 0; i < 4; ++i) { int e = pt + (i << 8);
        const u64 *pk = &tk[par * E + e], *pv = &tv[par * E + e], *pr = &tr[par * E + e];
        u64 qk = ld_tag(pk), qv = ld_tag(pv), qr = ld_tag(pr);
        TAGWAIT(qk, pk, tg); TAGWAIT(qv, pv, tg); TAGWAIT(qr, pr, tg);
        float kk = tagval(qk), vv = tagval(qv), rr = tagval(qr);
        float wwv = wf[i] + kk;
        float pm = fmaxf(wp[i], wwv);
        float e1 = expf(wp[i] - pm), e2 = expf(wwv - pm);
        float aa = e1 * wa[i] + e2 * vv, bb = e1 * wb[i] + e2;
        pool[3072 + e] = rr * aa / bb;                          // wkv
        float ww2 = wp[i] + wd[i];
        float p2 = fmaxf(ww2, kk);
        float f1 = expf(ww2 - p2), f2 = expf(kk - p2);
        if (bid == 0) {
          ostl[2 * E + e] = f1 * wa[i] + f2 * vv;
          ostl[3 * E + e] = f1 * wb[i] + f2;
          ostl[4 * E + e] = p2;
        }
      }
    }
    bar(); // B3: wkv ready
    if (!isPol) {
      const float4* v4 = (const float4*)(pool + 3072 + (wid & 3) * 256);
      float acc = warp_sum(dot4(wow0, v4[lane]));
      if (lane == 0) s_part[wid] = acc;
      if (wid < 4) {        // chunk 12+wid has same kc
        float acc2 = warp_sum(dot4(wow1, v4[lane]));
        if (lane == 0) s_part[12 + wid] = acc2;
      }
    }
    bar(); // B4
    if (tid < 4) {
      float dsum = s_part[tid * 4] + s_part[tid * 4 + 1] +
                   s_part[tid * 4 + 2] + s_part[tid * 4 + 3];
      stg_tag(&tsx[par * E + bid * 4 + tid], s_x[bid * 4 + tid] + dsum, tg);
    }

    // ================ Phase C: poll sx, LN2+mix (pollers); fkw/frw dots ================
    float4 wfr0, wfr1;
    float sx0, sx1, sx2, sx3;
    float c0[4], c1[4], c2[4], c3[4], c4[4];
    if (!isPol) {
      { int c = wid;
        wfr0 = ((const float4*)(p.frw + (size_t)l * E * E +
                 (size_t)(bid * 4 + (c >> 2)) * E + (c & 3) * 256))[lane]; }
      if (wid >= 4 && wid < 8) { int c = 8 + wid;
        wfr1 = ((const float4*)(p.frw + (size_t)l * E * E +
                 (size_t)(bid * 4 + (c >> 2)) * E + (c & 3) * 256))[lane]; }
      { int c = wid;
        pf_row4k(p.fvw + (size_t)l * E * H + (size_t)(bid * 4 + (c >> 2)) * H + (c & 3) * 1024,
                 r2 + c * 1024, lane); }
      if (wid >= 8) { int c = 4 + wid;
        pf_row4k(p.fvw + (size_t)l * E * H + (size_t)(bid * 4 + (c >> 2)) * H + (c & 3) * 1024,
                 r2 + c * 1024, lane); }
    } else {
#pragma unroll
      for (int i = 0; i < 4; ++i) { int e = pt + (i << 8);
        c0[i] = p.ln2_w[l * E + e]; c1[i] = p.ln2_b[l * E + e];
        c2[i] = stl[e]; c3[i] = p.ftmk[l * E + e]; c4[i] = p.ftmr[l * E + e];
      }
      const u64* b = tsx + par * E;
      u64 q0 = ld_tag(b + pt), q1 = ld_tag(b + pt + 256);
      u64 q2 = ld_tag(b + pt + 512), q3 = ld_tag(b + pt + 768);
      TAGWAIT(q0, b + pt, tg);       TAGWAIT(q1, b + pt + 256, tg);
      TAGWAIT(q2, b + pt + 512, tg); TAGWAIT(q3, b + pt + 768, tg);
      sx0 = tagval(q0); sx1 = tagval(q1); sx2 = tagval(q2); sx3 = tagval(q3);
      s_sx[pt] = sx0; s_sx[pt + 256] = sx1; s_sx[pt + 512] = sx2; s_sx[pt + 768] = sx3;
      float sa = sx0 + sx1 + sx2 + sx3;
      float sb = sx0 * sx0 + sx1 * sx1 + sx2 * sx2 + sx3 * sx3;
#pragma unroll
      for (int off = 32; off; off >>= 1) { sa += __shfl_xor(sa, off); sb += __shfl_xor(sb, off); }
      if (lane == 0) { s_red[2 * pw] = sa; s_red[2 * pw + 1] = sb; }
    }
    bar(); // B5
    if (isPol) {
      float s1 = s_red[0] + s_red[2] + s_red[4] + s_red[6];
      float s2 = s_red[1] + s_red[3] + s_red[5] + s_red[7];
      float m = s1 * (1.f / E), var = s2 * (1.f / E) - m * m;
      float is = 1.f / sqrtf(var + LN_EPS);
      float sxv[4] = { sx0, sx1, sx2, sx3 };
#pragma unroll
      for (int i = 0; i < 4; ++i) { int e = pt + (i << 8);
        float xn2 = (sxv[i] - m) * is * c0[i] + c1[i];
        pool[e]        = xn2 * c3[i] + c2[i] * (1.f - c3[i]);   // fxk
        pool[1024 + e] = xn2 * c4[i] + c2[i] * (1.f - c4[i]);   // fxr
        if (bid == 0) ostl[e] = xn2;                            // new ffn_x
      }
    }
    bar(); // B6: fxk/fxr ready
    if (!isPol) {
      // fkw resident: wait for (newer-than-fkw) = wfr + fvw (exact per class)
      if (wid < 4)      { WAITVM(5); }
      else if (wid < 8) { WAITVM(6); }
      else              { WAITVM(9); }
      float d = dotlds(wA, pool, lane);
      if (lane == 0) { float t = fmaxf(d, 0.f); stg_tag(&tfk[par * H + bid * 16 + wid], t * t, tg); }
      if (wid < 4) {
        float d2 = dotlds(r1 + (12 + wid) * 1024, pool, lane);
        if (lane == 0) { float t = fmaxf(d2, 0.f); stg_tag(&tfk[par * H + bid * 16 + 12 + wid], t * t, tg); }
      }
      const float4* f4 = (const float4*)(pool + 1024 + (wid & 3) * 256);
      float fp = warp_sum(dot4(wfr0, f4[lane]));
      if (lane == 0) s_part2[wid] = fp;
      if (wid >= 4 && wid < 8) {       // chunk 8+wid, same kc
        float fp2 = warp_sum(dot4(wfr1, f4[lane]));
        if (lane == 0) s_part2[8 + wid] = fp2;
      }
    }
    bar(); // B6.5: close fxk/fxr reads before fk relay overwrites pool

    // ================ Phase D: relay fk (pollers); fvw dots + residual ================
    if (!isPol) {
      if (l + 1 < NLAYER) {            // A(l+1) into own slot (fkw dot done above)
        const float* W = (matA == 0 ? p.kw : matA == 1 ? p.vw : p.rw) +
                         (size_t)(l + 1) * E * E + (size_t)rmA * E;
        pf_row4k(W, wA, lane);
      }
    } else {
      const u64* base = tfk + par * H;
#pragma unroll
      for (int g = 0; g < 4; ++g) {
        int o = pt + g * 1024;
        u64 q0 = ld_tag(base + o), q1 = ld_tag(base + o + 256);
        u64 q2 = ld_tag(base + o + 512), q3 = ld_tag(base + o + 768);
        TAGWAIT(q0, base + o, tg);       TAGWAIT(q1, base + o + 256, tg);
        TAGWAIT(q2, base + o + 512, tg); TAGWAIT(q3, base + o + 768, tg);
        pool[o] = tagval(q0); pool[o + 256] = tagval(q1);
        pool[o + 512] = tagval(q2); pool[o + 768] = tagval(q3);
      }
    }
    bar(); // B7: fk ready
    if (!isPol) {
      // fvw resident: newer = A'(4) + tfk stores; exact >=5 -> WAITVM(4) safe
      if (l + 1 < NLAYER) { WAITVM(4); } else { WAITVM(0); }
      { int c = wid;
        const float4* w4 = (const float4*)(r2 + c * 1024);
        const float4* v4 = (const float4*)(pool + (c & 3) * 1024);
        float acc = 0.f;
#pragma unroll
        for (int pc = 0; pc < 4; ++pc)
          acc += dot4(w4[lane + pc * 64], v4[lane + pc * 64]);
        acc = warp_sum(acc);
        if (lane == 0) s_part[c] = acc; }
      if (wid >= 8) { int c = 4 + wid;
        const float4* w4 = (const float4*)(r2 + c * 1024);
        const float4* v4 = (const float4*)(pool + (c & 3) * 1024);
        float acc = 0.f;
#pragma unroll
        for (int pc = 0; pc < 4; ++pc)
          acc += dot4(w4[lane + pc * 64], v4[lane + pc * 64]);
        acc = warp_sum(acc);
        if (lane == 0) s_part[c] = acc; }
    }
    bar(); // B8
    if (tid < 4) {
      float dsum = s_part[tid * 4] + s_part[tid * 4 + 1] +
                   s_part[tid * 4 + 2] + s_part[tid * 4 + 3];
      float frs  = s_part2[tid * 4] + s_part2[tid * 4 + 1] +
                   s_part2[tid * 4 + 2] + s_part2[tid * 4 + 3];
      float fr = 1.f / (1.f + expf(-frs));
      stg_tag(&tx[((l + 1) & 1) * E + bid * 4 + tid],
              s_sx[bid * 4 + tid] + fr * dsum, tg);
    }
  }

  // ================ Head: LN_out (pollers) + V x E matvec (all waves) ================
  {
    float hx0, hx1, hx2, hx3;
    float hw[4], hb[4];
    if (isPol) {
#pragma unroll
      for (int i = 0; i < 4; ++i) { int e = pt + (i << 8);
        hw[i] = p.lnow[e]; hb[i] = p.lnob[e];
      }
      const u64* b = tx + (NLAYER & 1) * E;
      u64 q0 = ld_tag(b + pt), q1 = ld_tag(b + pt + 256);
      u64 q2 = ld_tag(b + pt + 512), q3 = ld_tag(b + pt + 768);
      TAGWAIT(q0, b + pt, (unsigned)NLAYER);       TAGWAIT(q1, b + pt + 256, (unsigned)NLAYER);
      TAGWAIT(q2, b + pt + 512, (unsigned)NLAYER); TAGWAIT(q3, b + pt + 768, (unsigned)NLAYER);
      hx0 = tagval(q0); hx1 = tagval(q1); hx2 = tagval(q2); hx3 = tagval(q3);
      float sa = hx0 + hx1 + hx2 + hx3;
      float sb = hx0 * hx0 + hx1 * hx1 + hx2 * hx2 + hx3 * hx3;
#pragma unroll
      for (int off = 32; off; off >>= 1) { sa += __shfl_xor(sa, off); sb += __shfl_xor(sb, off); }
      if (lane == 0) { s_red[2 * pw] = sa; s_red[2 * pw + 1] = sb; }
    }
    bar();
    if (isPol) {
      float s1 = s_red[0] + s_red[2] + s_red[4] + s_red[6];
      float s2 = s_red[1] + s_red[3] + s_red[5] + s_red[7];
      float m = s1 * (1.f / E), var = s2 * (1.f / E) - m * m;
      float is = 1.f / sqrtf(var + LN_EPS);
      float hxv[4] = { hx0, hx1, hx2, hx3 };
#pragma unroll
      for (int i = 0; i < 4; ++i) { int e = pt + (i << 8);
        pool[e] = (hxv[i] - m) * is * hw[i] + hb[i];
      }
    }
    bar();
  }
  {
    const int gw = bid * 16 + wid;
    const float4* v4 = (const float4*)pool;
    float4 x0 = v4[lane], x1 = v4[lane + 64], x2 = v4[lane + 128], x3 = v4[lane + 192];
    int row = gw;
    for (; row + 12288 < V; row += 16384) {
      const float4* W0 = (const float4*)(p.headw + (size_t)row * E);
      const float4* W1 = (const float4*)(p.headw + (size_t)(row + 4096) * E);
      const float4* W2 = (const float4*)(p.headw + (size_t)(row + 8192) * E);
      const float4* W3 = (const float4*)(p.headw + (size_t)(row + 12288) * E);
      float a0 = 0.f, a1 = 0.f, a2 = 0.f, a3 = 0.f;
      a0 += dot4(W0[lane], x0) + dot4(W0[lane + 64], x1) + dot4(W0[lane + 128], x2) + dot4(W0[lane + 192], x3);
      a1 += dot4(W1[lane], x0) + dot4(W1[lane + 64], x1) + dot4(W1[lane + 128], x2) + dot4(W1[lane + 192], x3);
      a2 += dot4(W2[lane], x0) + dot4(W2[lane + 64], x1) + dot4(W2[lane + 128], x2) + dot4(W2[lane + 192], x3);
      a3 += dot4(W3[lane], x0) + dot4(W3[lane + 64], x1) + dot4(W3[lane + 128], x2) + dot4(W3[lane + 192], x3);
      a0 = warp_sum(a0); a1 = warp_sum(a1); a2 = warp_sum(a2); a3 = warp_sum(a3);
      if (lane == 0) {
        p.out[row] = a0; p.out[row + 4096] = a1;
        p.out[row + 8192] = a2; p.out[row + 12288] = a3;
      }
    }
    for (; row < V; row += 4096) {
      const float4* W0 = (const float4*)(p.headw + (size_t)row * E);
      float a0 = dot4(W0[lane], x0) + dot4(W0[lane + 64], x1) +
                 dot4(W0[lane + 128], x2) + dot4(W0[lane + 192], x3);
      a0 = warp_sum(a0);
      if (lane == 0) p.out[row] = a0;
    }
  }
}

extern "C" void kernel_launch(void* const* d_in, const int* in_sizes, int n_in,
                              void* d_out, int out_size, void* d_ws, size_t ws_size,
                              hipStream_t stream) {
  Params p;
  p.emb   = (const float*)d_in[0];
  p.ln0_w = (const float*)d_in[1];
  p.ln0_b = (const float*)d_in[2];
  p.ln1_w = (const float*)d_in[3];
  p.ln1_b = (const float*)d_in[4];
  p.tmk   = (const float*)d_in[5];
  p.tmv   = (const float*)d_in[6];
  p.tmr   = (const float*)d_in[7];
  p.tf    = (const float*)d_in[8];
  p.td    = (const float*)d_in[9];
  p.kw    = (const float*)d_in[10];
  p.vw    = (const float*)d_in[11];
  p.rw    = (const float*)d_in[12];
  p.ow    = (const float*)d_in[13];
  p.ln2_w = (const float*)d_in[14];
  p.ln2_b = (const float*)d_in[15];
  p.ftmk  = (const float*)d_in[16];
  p.ftmr  = (const float*)d_in[17];
  p.fkw   = (const float*)d_in[18];
  p.fvw   = (const float*)d_in[19];
  p.frw   = (const float*)d_in[20];
  p.lnow  = (const float*)d_in[21];
  p.lnob  = (const float*)d_in[22];
  p.headw = (const float*)d_in[23];
  if (in_sizes[24] == 1) {
    p.tok = (const int*)d_in[24];
    p.st  = (const float*)d_in[25];
  } else {
    p.st  = (const float*)d_in[24];
    p.tok = (const int*)d_in[25];
  }
  p.out   = (float*)d_out;
  p.ws    = (float*)d_ws;

  // zero ALL tag words each launch (graph node): (10E + 2H) u64 = 147456 B
  hipMemsetAsync(d_ws, 0, (10 * E + 2 * H) * sizeof(unsigned long long), stream);

  void* args[] = { &p };
  hipLaunchCooperativeKernel((const void*)rwkv_kernel, dim3(NB), dim3(NT),
                             args, SMEMF * sizeof(float), stream);
}

// Round 19
// 554.636 us; speedup vs baseline: 1.5577x; 1.5577x over previous
//
#include <hip/hip_runtime.h>

#define E 1024
#define H 4096
#define NLAYER 24
#define V 50277
#define NB 256
#define NT 1024
#define LN_EPS 1e-5f

typedef unsigned long long u64;

// ---- LDS float offsets (dynamic shared, 160000 B) ----
// R1 (16 slots x 1024): A(l) rows (w<12) -> fkw(l) (all 16) -> A(l+1)
// R2 (4 rows x 4096): fvw(l) row r=w>>2, chunk w&3 -- wave-private
#define R1O    0
#define R2O    16384
#define POOLO  32768   // 4096: xk|xv|xr|wkv (A/B); fxk (C); fk (D)
#define SXO    36864   // 1024
#define SSXO   37888   // 1024
#define FXRO   38912   // 1024
#define REDO   39936   // 32
#define PARTO  39968   // 16
#define PART2O 39984   // 16
#define SMEMF  40000

struct Params {
  const float* emb;   const float* ln0_w; const float* ln0_b;
  const float* ln1_w; const float* ln1_b;
  const float* tmk;   const float* tmv;   const float* tmr;
  const float* tf;    const float* td;
  const float* kw;    const float* vw;    const float* rw;  const float* ow;
  const float* ln2_w; const float* ln2_b;
  const float* ftmk;  const float* ftmr;
  const float* fkw;   const float* fvw;   const float* frw;
  const float* lnow;  const float* lnob;  const float* headw;
  const float* st;    const int* tok;
  float* out; float* ws;
};

// ---- tagged 8-byte dataflow handoff (relaxed agent scope) ----
__device__ __forceinline__ void stg_tag(u64* p, float v, unsigned tag) {
  u64 w = ((u64)__float_as_uint(v) << 32) | (u64)tag;
  __hip_atomic_store(p, w, __ATOMIC_RELAXED, __HIP_MEMORY_SCOPE_AGENT);
}
__device__ __forceinline__ u64 ld_tag(const u64* p) {
  return __hip_atomic_load(p, __ATOMIC_RELAXED, __HIP_MEMORY_SCOPE_AGENT);
}
__device__ __forceinline__ float poll_tag(const u64* p, unsigned tag) {
  u64 w = ld_tag(p);
  while ((unsigned)w != tag) { __builtin_amdgcn_s_sleep(1); w = ld_tag(p); }
  return __uint_as_float((unsigned)(w >> 32));
}

__device__ __forceinline__ void wait_pf() {
  asm volatile("s_waitcnt vmcnt(0)" ::: "memory");
}

// zero-VGPR global->LDS DMA: 64 lanes x 16 B = 1 KB per call.
__device__ __forceinline__ void gload_lds16(const float* g, float* l) {
  __builtin_amdgcn_global_load_lds(
      (const __attribute__((address_space(1))) unsigned int*)(g),
      (__attribute__((address_space(3))) unsigned int*)(l), 16, 0, 0);
}
__device__ __forceinline__ void pf_row4k(const float* row, float* dst, int lane) {
#pragma unroll
  for (int c = 0; c < 4; ++c)
    gload_lds16(row + c * 256 + lane * 4, dst + c * 256);
}

__device__ __forceinline__ float warp_sum(float v) {
#pragma unroll
  for (int off = 32; off; off >>= 1) v += __shfl_down(v, off);
  return v;
}

// single-sync LN stats: returns (mean, var)
__device__ __forceinline__ float2 ln_stats(float v, float* red) {
  float a = v, b = v * v;
#pragma unroll
  for (int off = 32; off; off >>= 1) { a += __shfl_xor(a, off); b += __shfl_xor(b, off); }
  const int wid = threadIdx.x >> 6, lane = threadIdx.x & 63;
  if (lane == 0) { red[2 * wid] = a; red[2 * wid + 1] = b; }
  __syncthreads();
  float s1 = 0.f, s2 = 0.f;
  const float2* r2 = (const float2*)red;
#pragma unroll
  for (int j = 0; j < 16; ++j) { float2 t = r2[j]; s1 += t.x; s2 += t.y; }
  float m = s1 * (1.f / E);
  return make_float2(m, s2 * (1.f / E) - m * m);
}

__device__ __forceinline__ float dot4(float4 a, float4 b) {
  return a.x * b.x + a.y * b.y + a.z * b.z + a.w * b.w;
}

__device__ __forceinline__ float dotlds(const float* wrow, const float* vec, int lane) {
  const float4* w4 = (const float4*)wrow;
  const float4* v4 = (const float4*)vec;
  float acc = 0.f;
#pragma unroll
  for (int p = 0; p < 4; ++p)
    acc += dot4(w4[lane + p * 64], v4[lane + p * 64]);
  return warp_sum(acc);
}

__global__ __launch_bounds__(NT, 1) void rwkv_kernel(Params p) {
  const int tid = threadIdx.x, bid = blockIdx.x;
  const int lane = tid & 63, wid = tid >> 6;

  extern __shared__ float smem[];
  float* r1     = smem + R1O;
  float* r2     = smem + R2O;
  float* pool   = smem + POOLO;
  float* s_x    = smem + SXO;
  float* s_sx   = smem + SSXO;
  float* s_fxr  = smem + FXRO;
  float* s_red  = smem + REDO;
  float* s_part = smem + PARTO;
  float* s_part2= smem + PART2O;

  u64* tws = (u64*)p.ws;
  u64* tk  = tws;             // [2][E]
  u64* tv  = tws + 2 * E;
  u64* tr  = tws + 4 * E;
  u64* tsx = tws + 6 * E;
  u64* tx  = tws + 8 * E;
  u64* tfk = tws + 10 * E;    // [2][H]

  float* out_st = p.out + V;
  const int token = p.tok[0];

  // wave->work mappings
  const bool hasA = wid < 12;
  const int rA = bid * 12 + wid;
  const int matA = rA >> 10, rmA = rA & (E - 1);
  const int rloc = wid >> 2, kc = wid & 3;       // ow/frw/fvw: row bid*4+rloc, chunk kc
  const int rowO = bid * 4 + rloc;
  float* wA = r1 + wid * 1024;                   // wave-private R1 slot
  float* wD = r2 + rloc * 4096 + kc * 1024;      // wave-private R2 slot

  // ---- init: A(0) DMA ----
  if (hasA) {
    const float* W = (matA == 0 ? p.kw : matA == 1 ? p.vw : p.rw) + (size_t)rmA * E;
    pf_row4k(W, wA, lane);
  }

  // LN0
  {
    float v = p.emb[(size_t)token * E + tid];
    float2 mv = ln_stats(v, s_red);
    s_x[tid] = (v - mv.x) / sqrtf(mv.y + LN_EPS) * p.ln0_w[tid] + p.ln0_b[tid];
  }

  for (int l = 0; l < NLAYER; ++l) {
    const float* stl = p.st + (size_t)5 * l * E;
    float* ostl = out_st + (size_t)5 * l * E;
    const int par = l & 1;
    const unsigned tg = (unsigned)(l + 1);

    // ================ Phase A: LN1 + mix + k/v/r matvec ================
    // param loads issued before the poll -> they stream during the wait
    float l1w = p.ln1_w[l * E + tid], l1b = p.ln1_b[l * E + tid];
    float ax = stl[E + tid];
    float ta = p.tmk[l * E + tid], tb = p.tmv[l * E + tid], tc = p.tmr[l * E + tid];
    float xv_;
    if (l > 0) { xv_ = poll_tag(&tx[par * E + tid], (unsigned)l); s_x[tid] = xv_; }
    else       { xv_ = s_x[tid]; }
    {
      float2 mv = ln_stats(xv_, s_red);                       // SYNC 1
      float xn = (xv_ - mv.x) / sqrtf(mv.y + LN_EPS) * l1w + l1b;
      pool[tid]        = xn * ta + ax * (1.f - ta);           // xk
      pool[1024 + tid] = xn * tb + ax * (1.f - tb);           // xv
      pool[2048 + tid] = xn * tc + ax * (1.f - tc);           // xr
      if (bid == 0) ostl[E + tid] = xn;                       // new att_x
    }
    __syncthreads();                                          // SYNC 2
    wait_pf();   // l==0: init DMA; l>0: no-op (drained by tx poll)
    if (hasA) {
      float d = dotlds(wA, pool + matA * 1024, lane);
      if (lane == 0) {
        u64* dst = (matA == 0 ? tk : matA == 1 ? tv : tr) + par * E + rmA;
        stg_tag(dst, matA == 2 ? 1.f / (1.f + expf(-d)) : d, tg);
      }
    }

    // ================ Phase B: WKV + ow matvec ================
    {
      // 1) small register loads (land during the poll wait)
      float aav = stl[2 * E + tid], bbv = stl[3 * E + tid], ppv = stl[4 * E + tid];
      float tfv = p.tf[l * E + tid], tdv = p.td[l * E + tid];
      float4 wow = ((const float4*)(p.ow + (size_t)l * E * E + (size_t)rowO * E + kc * 256))[lane];
      // 2) DMA for phase C: fkw row (streams during the poll wait)
      pf_row4k(p.fkw + (size_t)l * H * E + (size_t)(bid * 16 + wid) * E, wA, lane);
      // 3) poll own k/v/r element (drains loads+DMA as a side effect -- free)
      const u64 *bk = tk + par * E + tid, *bv = tv + par * E + tid, *br = tr + par * E + tid;
      u64 wk = ld_tag(bk), wv = ld_tag(bv), wr = ld_tag(br);
      while ((unsigned)wk != tg) { __builtin_amdgcn_s_sleep(1); wk = ld_tag(bk); }
      while ((unsigned)wv != tg) { __builtin_amdgcn_s_sleep(1); wv = ld_tag(bv); }
      while ((unsigned)wr != tg) { __builtin_amdgcn_s_sleep(1); wr = ld_tag(br); }
      float kk = __uint_as_float((unsigned)(wk >> 32));
      float vv = __uint_as_float((unsigned)(wv >> 32));
      float rr = __uint_as_float((unsigned)(wr >> 32));
      // 4) WKV compute
      float wwv = tfv + kk;
      float pm = fmaxf(ppv, wwv);
      float e1 = expf(ppv - pm), e2 = expf(wwv - pm);
      float a = e1 * aav + e2 * vv, b = e1 * bbv + e2;
      pool[3072 + tid] = rr * a / b;                          // wkv
      float ww2 = ppv + tdv;
      float p2 = fmaxf(ww2, kk);
      float f1 = expf(ww2 - p2), f2 = expf(kk - p2);
      if (bid == 0) {
        ostl[2 * E + tid] = f1 * aav + f2 * vv;               // naa
        ostl[3 * E + tid] = f1 * bbv + f2;                    // nbb
        ostl[4 * E + tid] = p2;                               // npp
      }
      __syncthreads();                                        // SYNC 3 (wkv ready)
      const float4* v4 = (const float4*)(pool + 3072 + kc * 256);
      float acc = warp_sum(dot4(wow, v4[lane]));
      if (lane == 0) s_part[wid] = acc;
    }
    __syncthreads();                                          // SYNC 4
    if (tid < 4) {
      float dsum = s_part[tid * 4] + s_part[tid * 4 + 1] +
                   s_part[tid * 4 + 2] + s_part[tid * 4 + 3];
      stg_tag(&tsx[par * E + bid * 4 + tid], s_x[bid * 4 + tid] + dsum, tg);
    }

    // ================ Phase C: LN2 + mix + fkw matvec + frw partials ================
    {
      // 1) small register loads (land during the poll wait)
      float l2w = p.ln2_w[l * E + tid], l2b = p.ln2_b[l * E + tid];
      float fx = stl[tid];
      float fa = p.ftmk[l * E + tid], fb = p.ftmr[l * E + tid];
      float4 wfr = ((const float4*)(p.frw + (size_t)l * E * E + (size_t)rowO * E + kc * 256))[lane];
      // 2) DMA for phase D: fvw chunk (streams during the poll wait; wD wave-private)
      pf_row4k(p.fvw + (size_t)l * E * H + (size_t)rowO * H + kc * 1024, wD, lane);
      // 3) poll sx
      float sxv = poll_tag(&tsx[par * E + tid], tg);
      s_sx[tid] = sxv;
      // 4) LN2 + mix
      float2 mv = ln_stats(sxv, s_red);                       // SYNC 5
      float xn2 = (sxv - mv.x) / sqrtf(mv.y + LN_EPS) * l2w + l2b;
      pool[tid]  = xn2 * fa + fx * (1.f - fa);                // fxk
      s_fxr[tid] = xn2 * fb + fx * (1.f - fb);
      if (bid == 0) ostl[tid] = xn2;                          // new ffn_x
      __syncthreads();                                        // SYNC 6
      float d = dotlds(wA, pool, lane);                       // fkw row (resident)
      if (lane == 0) { float t = fmaxf(d, 0.f); stg_tag(&tfk[par * H + bid * 16 + wid], t * t, tg); }
      const float4* f4 = (const float4*)(s_fxr + kc * 256);
      float fp = warp_sum(dot4(wfr, f4[lane]));               // frw partial
      if (lane == 0) s_part2[wid] = fp;
    }

    // ================ Phase D: fvw matvec + residual ================
    // issue A(l+1) DMA first (own R1 slot; fkw dot completed in program order)
    if (l + 1 < NLAYER && hasA) {
      const float* W = (matA == 0 ? p.kw : matA == 1 ? p.vw : p.rw) +
                       (size_t)(l + 1) * E * E + (size_t)rmA * E;
      pf_row4k(W, wA, lane);
    }
    __syncthreads();             // SYNC 7: close C's pool/s_fxr reads before relay
    {
      // poll fk (drains C's fvw DMA + A' DMA -- both streamed during waits)
      const u64* base = tfk + par * H;
      u64 w0 = ld_tag(base + tid);
      u64 w1 = ld_tag(base + tid + 1024);
      u64 w2 = ld_tag(base + tid + 2048);
      u64 w3 = ld_tag(base + tid + 3072);
      while ((unsigned)w0 != tg) { __builtin_amdgcn_s_sleep(1); w0 = ld_tag(base + tid); }
      while ((unsigned)w1 != tg) { __builtin_amdgcn_s_sleep(1); w1 = ld_tag(base + tid + 1024); }
      while ((unsigned)w2 != tg) { __builtin_amdgcn_s_sleep(1); w2 = ld_tag(base + tid + 2048); }
      while ((unsigned)w3 != tg) { __builtin_amdgcn_s_sleep(1); w3 = ld_tag(base + tid + 3072); }
      pool[tid]        = __uint_as_float((unsigned)(w0 >> 32));
      pool[tid + 1024] = __uint_as_float((unsigned)(w1 >> 32));
      pool[tid + 2048] = __uint_as_float((unsigned)(w2 >> 32));
      pool[tid + 3072] = __uint_as_float((unsigned)(w3 >> 32));
    }
    __syncthreads();             // SYNC 8: fk relay complete
    {
      const float4* v4 = (const float4*)(pool + kc * 1024);
      const float4* w4 = (const float4*)wD;                   // own slot (drained)
      float acc = 0.f;
#pragma unroll
      for (int pc = 0; pc < 4; ++pc)
        acc += dot4(w4[lane + pc * 64], v4[lane + pc * 64]);
      acc = warp_sum(acc);
      if (lane == 0) s_part[wid] = acc;
    }
    __syncthreads();             // SYNC 9
    if (tid < 4) {
      float dsum = s_part[tid * 4] + s_part[tid * 4 + 1] +
                   s_part[tid * 4 + 2] + s_part[tid * 4 + 3];
      float frs  = s_part2[tid * 4] + s_part2[tid * 4 + 1] +
                   s_part2[tid * 4 + 2] + s_part2[tid * 4 + 3];
      float fr = 1.f / (1.f + expf(-frs));
      stg_tag(&tx[((l + 1) & 1) * E + bid * 4 + tid],
              s_sx[bid * 4 + tid] + fr * dsum, tg);
    }
  }

  // ================ Head: LN_out + V x E matvec (4-way rows) ================
  {
    float xv_ = poll_tag(&tx[(NLAYER & 1) * E + tid], (unsigned)NLAYER);
    float2 mv = ln_stats(xv_, s_red);
    pool[tid] = (xv_ - mv.x) / sqrtf(mv.y + LN_EPS) * p.lnow[tid] + p.lnob[tid];
  }
  __syncthreads();
  {
    const int gw = bid * 16 + wid;
    const float4* v4 = (const float4*)pool;
    float4 x0 = v4[lane], x1 = v4[lane + 64], x2 = v4[lane + 128], x3 = v4[lane + 192];
    int row = gw;
    for (; row + 12288 < V; row += 16384) {
      const float4* W0 = (const float4*)(p.headw + (size_t)row * E);
      const float4* W1 = (const float4*)(p.headw + (size_t)(row + 4096) * E);
      const float4* W2 = (const float4*)(p.headw + (size_t)(row + 8192) * E);
      const float4* W3 = (const float4*)(p.headw + (size_t)(row + 12288) * E);
      float a0 = 0.f, a1 = 0.f, a2 = 0.f, a3 = 0.f;
      a0 += dot4(W0[lane], x0) + dot4(W0[lane + 64], x1) + dot4(W0[lane + 128], x2) + dot4(W0[lane + 192], x3);
      a1 += dot4(W1[lane], x0) + dot4(W1[lane + 64], x1) + dot4(W1[lane + 128], x2) + dot4(W1[lane + 192], x3);
      a2 += dot4(W2[lane], x0) + dot4(W2[lane + 64], x1) + dot4(W2[lane + 128], x2) + dot4(W2[lane + 192], x3);
      a3 += dot4(W3[lane], x0) + dot4(W3[lane + 64], x1) + dot4(W3[lane + 128], x2) + dot4(W3[lane + 192], x3);
      a0 = warp_sum(a0); a1 = warp_sum(a1); a2 = warp_sum(a2); a3 = warp_sum(a3);
      if (lane == 0) {
        p.out[row] = a0; p.out[row + 4096] = a1;
        p.out[row + 8192] = a2; p.out[row + 12288] = a3;
      }
    }
    for (; row < V; row += 4096) {
      const float4* W0 = (const float4*)(p.headw + (size_t)row * E);
      float a0 = dot4(W0[lane], x0) + dot4(W0[lane + 64], x1) +
                 dot4(W0[lane + 128], x2) + dot4(W0[lane + 192], x3);
      a0 = warp_sum(a0);
      if (lane == 0) p.out[row] = a0;
    }
  }
}

extern "C" void kernel_launch(void* const* d_in, const int* in_sizes, int n_in,
                              void* d_out, int out_size, void* d_ws, size_t ws_size,
                              hipStream_t stream) {
  Params p;
  p.emb   = (const float*)d_in[0];
  p.ln0_w = (const float*)d_in[1];
  p.ln0_b = (const float*)d_in[2];
  p.ln1_w = (const float*)d_in[3];
  p.ln1_b = (const float*)d_in[4];
  p.tmk   = (const float*)d_in[5];
  p.tmv   = (const float*)d_in[6];
  p.tmr   = (const float*)d_in[7];
  p.tf    = (const float*)d_in[8];
  p.td    = (const float*)d_in[9];
  p.kw    = (const float*)d_in[10];
  p.vw    = (const float*)d_in[11];
  p.rw    = (const float*)d_in[12];
  p.ow    = (const float*)d_in[13];
  p.ln2_w = (const float*)d_in[14];
  p.ln2_b = (const float*)d_in[15];
  p.ftmk  = (const float*)d_in[16];
  p.ftmr  = (const float*)d_in[17];
  p.fkw   = (const float*)d_in[18];
  p.fvw   = (const float*)d_in[19];
  p.frw   = (const float*)d_in[20];
  p.lnow  = (const float*)d_in[21];
  p.lnob  = (const float*)d_in[22];
  p.headw = (const float*)d_in[23];
  if (in_sizes[24] == 1) {
    p.tok = (const int*)d_in[24];
    p.st  = (const float*)d_in[25];
  } else {
    p.st  = (const float*)d_in[24];
    p.tok = (const int*)d_in[25];
  }
  p.out   = (float*)d_out;
  p.ws    = (float*)d_ws;

  // zero ALL tag words each launch (graph node): (10E + 2H) u64 = 147456 B
  hipMemsetAsync(d_ws, 0, (10 * E + 2 * H) * sizeof(unsigned long long), stream);

  void* args[] = { &p };
  hipLaunchCooperativeKernel((const void*)rwkv_kernel, dim3(NB), dim3(NT),
                             args, SMEMF * sizeof(float), stream);
}

// Round 20
// 487.697 us; speedup vs baseline: 1.7715x; 1.1373x over previous
//
#include <hip/hip_runtime.h>

#define E 1024
#define H 4096
#define NLAYER 24
#define V 50277
#define NB 256
#define NT 1024
#define LN_EPS 1e-5f

typedef unsigned long long u64;

// ---- LDS float offsets (dynamic shared, 160000 B) ----
// R1 (16 slots x 1024): A(l) rows (w<12: mat w>>2, row bid*4+(w&3)) -> fkw(l) -> A(l+1)
// R2 (4 rows x 4096): fvw(l) row r=w>>2, chunk w&3 -- wave-private
#define R1O    0
#define R2O    16384
#define POOLO  32768   // 4096: xk|xv|xr|wkv (A/B); fxk (C); fk (D)
#define SXO    36864   // 1024
#define SSXO   37888   // 1024
#define FXRO   38912   // 1024
#define REDO   39936   // 32
#define PARTO  39968   // 16
#define PART2O 39984   // 16
#define SMEMF  40000

struct Params {
  const float* emb;   const float* ln0_w; const float* ln0_b;
  const float* ln1_w; const float* ln1_b;
  const float* tmk;   const float* tmv;   const float* tmr;
  const float* tf;    const float* td;
  const float* kw;    const float* vw;    const float* rw;  const float* ow;
  const float* ln2_w; const float* ln2_b;
  const float* ftmk;  const float* ftmr;
  const float* fkw;   const float* fvw;   const float* frw;
  const float* lnow;  const float* lnob;  const float* headw;
  const float* st;    const int* tok;
  float* out; float* ws;
};

// ---- tagged 8-byte dataflow handoff (relaxed agent scope) ----
__device__ __forceinline__ void stg_tag(u64* p, float v, unsigned tag) {
  u64 w = ((u64)__float_as_uint(v) << 32) | (u64)tag;
  __hip_atomic_store(p, w, __ATOMIC_RELAXED, __HIP_MEMORY_SCOPE_AGENT);
}
__device__ __forceinline__ u64 ld_tag(const u64* p) {
  return __hip_atomic_load(p, __ATOMIC_RELAXED, __HIP_MEMORY_SCOPE_AGENT);
}
__device__ __forceinline__ float poll_tag(const u64* p, unsigned tag) {
  u64 w = ld_tag(p);
  while ((unsigned)w != tag) { __builtin_amdgcn_s_sleep(1); w = ld_tag(p); }
  return __uint_as_float((unsigned)(w >> 32));
}

__device__ __forceinline__ void wait_pf() {
  asm volatile("s_waitcnt vmcnt(0)" ::: "memory");
}

// zero-VGPR global->LDS DMA: 64 lanes x 16 B = 1 KB per call.
__device__ __forceinline__ void gload_lds16(const float* g, float* l) {
  __builtin_amdgcn_global_load_lds(
      (const __attribute__((address_space(1))) unsigned int*)(g),
      (__attribute__((address_space(3))) unsigned int*)(l), 16, 0, 0);
}
__device__ __forceinline__ void pf_row4k(const float* row, float* dst, int lane) {
#pragma unroll
  for (int c = 0; c < 4; ++c)
    gload_lds16(row + c * 256 + lane * 4, dst + c * 256);
}

__device__ __forceinline__ float warp_sum(float v) {
#pragma unroll
  for (int off = 32; off; off >>= 1) v += __shfl_down(v, off);
  return v;
}

// single-sync LN stats: returns (mean, var)
__device__ __forceinline__ float2 ln_stats(float v, float* red) {
  float a = v, b = v * v;
#pragma unroll
  for (int off = 32; off; off >>= 1) { a += __shfl_xor(a, off); b += __shfl_xor(b, off); }
  const int wid = threadIdx.x >> 6, lane = threadIdx.x & 63;
  if (lane == 0) { red[2 * wid] = a; red[2 * wid + 1] = b; }
  __syncthreads();
  float s1 = 0.f, s2 = 0.f;
  const float2* r2 = (const float2*)red;
#pragma unroll
  for (int j = 0; j < 16; ++j) { float2 t = r2[j]; s1 += t.x; s2 += t.y; }
  float m = s1 * (1.f / E);
  return make_float2(m, s2 * (1.f / E) - m * m);
}

__device__ __forceinline__ float dot4(float4 a, float4 b) {
  return a.x * b.x + a.y * b.y + a.z * b.z + a.w * b.w;
}

__device__ __forceinline__ float dotlds(const float* wrow, const float* vec, int lane) {
  const float4* w4 = (const float4*)wrow;
  const float4* v4 = (const float4*)vec;
  float acc = 0.f;
#pragma unroll
  for (int p = 0; p < 4; ++p)
    acc += dot4(w4[lane + p * 64], v4[lane + p * 64]);
  return warp_sum(acc);
}

__global__ __launch_bounds__(NT, 1) void rwkv_kernel(Params p) {
  const int tid = threadIdx.x, bid = blockIdx.x;
  const int lane = tid & 63, wid = tid >> 6;

  extern __shared__ float smem[];
  float* r1     = smem + R1O;
  float* r2     = smem + R2O;
  float* pool   = smem + POOLO;
  float* s_x    = smem + SXO;
  float* s_sx   = smem + SSXO;
  float* s_fxr  = smem + FXRO;
  float* s_red  = smem + REDO;
  float* s_part = smem + PARTO;
  float* s_part2= smem + PART2O;

  u64* tws = (u64*)p.ws;
  u64* twk = tws;             // [2][E]  (wkv handoff; slots of old tk)
  u64* tsx = tws + 6 * E;
  u64* tx  = tws + 8 * E;
  u64* tfk = tws + 10 * E;    // [2][H]

  float* out_st = p.out + V;
  const int token = p.tok[0];

  // wave->work mappings
  const bool hasA = wid < 12;
  const int matA = wid >> 2;                     // 0:kw 1:vw 2:rw  (wid<12)
  const int rowA = bid * 4 + (wid & 3);          // LOCAL rows: block owns its 4 elems
  const int rloc = wid >> 2, kc = wid & 3;       // ow/frw/fvw: row bid*4+rloc, chunk kc
  const int rowO = bid * 4 + rloc;
  float* wA = r1 + wid * 1024;                   // wave-private R1 slot
  float* wD = r2 + rloc * 4096 + kc * 1024;      // wave-private R2 slot

  // ---- init: A(0) DMA ----
  if (hasA) {
    const float* W = (matA == 0 ? p.kw : matA == 1 ? p.vw : p.rw) + (size_t)rowA * E;
    pf_row4k(W, wA, lane);
  }

  // LN0
  {
    float v = p.emb[(size_t)token * E + tid];
    float2 mv = ln_stats(v, s_red);
    s_x[tid] = (v - mv.x) / sqrtf(mv.y + LN_EPS) * p.ln0_w[tid] + p.ln0_b[tid];
  }

  for (int l = 0; l < NLAYER; ++l) {
    const float* stl = p.st + (size_t)5 * l * E;
    float* ostl = out_st + (size_t)5 * l * E;
    const int par = l & 1;
    const unsigned tg = (unsigned)(l + 1);

    // ================ Phase A: LN1 + mix + k/v/r dots + LOCAL WKV ================
    // param loads issued before the poll -> they stream during the wait
    float l1w = p.ln1_w[l * E + tid], l1b = p.ln1_b[l * E + tid];
    float ax = stl[E + tid];
    float ta = p.tmk[l * E + tid], tb = p.tmv[l * E + tid], tc = p.tmr[l * E + tid];
    // owner threads preload state+params for their element (hidden under poll)
    float aav, bbv, ppv, tfv, tdv;
    const int eOwn = bid * 4 + tid;              // valid when tid<4
    if (tid < 4) {
      aav = stl[2 * E + eOwn]; bbv = stl[3 * E + eOwn]; ppv = stl[4 * E + eOwn];
      tfv = p.tf[l * E + eOwn]; tdv = p.td[l * E + eOwn];
    }
    float xv_;
    if (l > 0) { xv_ = poll_tag(&tx[par * E + tid], (unsigned)l); s_x[tid] = xv_; }
    else       { xv_ = s_x[tid]; }
    {
      float2 mv = ln_stats(xv_, s_red);                       // SYNC 1
      float xn = (xv_ - mv.x) / sqrtf(mv.y + LN_EPS) * l1w + l1b;
      pool[tid]        = xn * ta + ax * (1.f - ta);           // xk
      pool[1024 + tid] = xn * tb + ax * (1.f - tb);           // xv
      pool[2048 + tid] = xn * tc + ax * (1.f - tc);           // xr
      if (bid == 0) ostl[E + tid] = xn;                       // new att_x
    }
    __syncthreads();                                          // SYNC 2
    wait_pf();   // l==0: init DMA; l>0: no-op (drained by tx poll)
    if (hasA) {
      float d = dotlds(wA, pool + matA * 1024, lane);
      if (lane == 0) s_part[wid] = d;           // k:0-3, v:4-7, r:8-11 (elem wid&3)
    }
    __syncthreads();                                          // SYNC 2.5
    if (tid < 4) {    // local WKV for element eOwn; single tag handoff
      float kk = s_part[tid], vv = s_part[4 + tid];
      float rr = 1.f / (1.f + expf(-s_part[8 + tid]));
      float wwv = tfv + kk;
      float pm = fmaxf(ppv, wwv);
      float e1 = expf(ppv - pm), e2 = expf(wwv - pm);
      float a = e1 * aav + e2 * vv, b = e1 * bbv + e2;
      stg_tag(&twk[par * E + eOwn], rr * a / b, tg);
      float ww2 = ppv + tdv;
      float p2 = fmaxf(ww2, kk);
      float f1 = expf(ww2 - p2), f2 = expf(kk - p2);
      ostl[2 * E + eOwn] = f1 * aav + f2 * vv;                // naa
      ostl[3 * E + eOwn] = f1 * bbv + f2;                     // nbb
      ostl[4 * E + eOwn] = p2;                                // npp
    }

    // ================ Phase B: wkv poll + ow matvec ================
    {
      // 1) register load + DMA issued before the poll (stream during wait)
      float4 wow = ((const float4*)(p.ow + (size_t)l * E * E + (size_t)rowO * E + kc * 256))[lane];
      pf_row4k(p.fkw + (size_t)l * H * E + (size_t)(bid * 16 + wid) * E, wA, lane);
      // 2) poll own wkv element (single tag, single producer)
      pool[3072 + tid] = poll_tag(&twk[par * E + tid], tg);
      __syncthreads();                                        // SYNC 3 (wkv ready)
      const float4* v4 = (const float4*)(pool + 3072 + kc * 256);
      float acc = warp_sum(dot4(wow, v4[lane]));
      if (lane == 0) s_part[wid] = acc;
    }
    __syncthreads();                                          // SYNC 4
    if (tid < 4) {
      float dsum = s_part[tid * 4] + s_part[tid * 4 + 1] +
                   s_part[tid * 4 + 2] + s_part[tid * 4 + 3];
      stg_tag(&tsx[par * E + bid * 4 + tid], s_x[bid * 4 + tid] + dsum, tg);
    }

    // ================ Phase C: LN2 + mix + fkw matvec + frw partials ================
    {
      // 1) small register loads (land during the poll wait)
      float l2w = p.ln2_w[l * E + tid], l2b = p.ln2_b[l * E + tid];
      float fx = stl[tid];
      float fa = p.ftmk[l * E + tid], fb = p.ftmr[l * E + tid];
      float4 wfr = ((const float4*)(p.frw + (size_t)l * E * E + (size_t)rowO * E + kc * 256))[lane];
      // 2) DMA for phase D: fvw chunk (streams during the poll wait; wD wave-private)
      pf_row4k(p.fvw + (size_t)l * E * H + (size_t)rowO * H + kc * 1024, wD, lane);
      // 3) poll sx
      float sxv = poll_tag(&tsx[par * E + tid], tg);
      s_sx[tid] = sxv;
      // 4) LN2 + mix
      float2 mv = ln_stats(sxv, s_red);                       // SYNC 5
      float xn2 = (sxv - mv.x) / sqrtf(mv.y + LN_EPS) * l2w + l2b;
      pool[tid]  = xn2 * fa + fx * (1.f - fa);                // fxk
      s_fxr[tid] = xn2 * fb + fx * (1.f - fb);
      if (bid == 0) ostl[tid] = xn2;                          // new ffn_x
      __syncthreads();                                        // SYNC 6
      float d = dotlds(wA, pool, lane);                       // fkw row (resident)
      if (lane == 0) { float t = fmaxf(d, 0.f); stg_tag(&tfk[par * H + bid * 16 + wid], t * t, tg); }
      const float4* f4 = (const float4*)(s_fxr + kc * 256);
      float fp = warp_sum(dot4(wfr, f4[lane]));               // frw partial
      if (lane == 0) s_part2[wid] = fp;
    }

    // ================ Phase D: fvw matvec + residual ================
    // issue A(l+1) DMA first (own R1 slot; fkw dot completed in program order)
    if (l + 1 < NLAYER && hasA) {
      const float* W = (matA == 0 ? p.kw : matA == 1 ? p.vw : p.rw) +
                       (size_t)(l + 1) * E * E + (size_t)rowA * E;
      pf_row4k(W, wA, lane);
    }
    __syncthreads();             // SYNC 7: close C's pool/s_fxr reads before relay
    {
      // poll fk (drains C's fvw DMA + A' DMA -- both streamed during waits)
      const u64* base = tfk + par * H;
      u64 w0 = ld_tag(base + tid);
      u64 w1 = ld_tag(base + tid + 1024);
      u64 w2 = ld_tag(base + tid + 2048);
      u64 w3 = ld_tag(base + tid + 3072);
      while ((unsigned)w0 != tg) { __builtin_amdgcn_s_sleep(1); w0 = ld_tag(base + tid); }
      while ((unsigned)w1 != tg) { __builtin_amdgcn_s_sleep(1); w1 = ld_tag(base + tid + 1024); }
      while ((unsigned)w2 != tg) { __builtin_amdgcn_s_sleep(1); w2 = ld_tag(base + tid + 2048); }
      while ((unsigned)w3 != tg) { __builtin_amdgcn_s_sleep(1); w3 = ld_tag(base + tid + 3072); }
      pool[tid]        = __uint_as_float((unsigned)(w0 >> 32));
      pool[tid + 1024] = __uint_as_float((unsigned)(w1 >> 32));
      pool[tid + 2048] = __uint_as_float((unsigned)(w2 >> 32));
      pool[tid + 3072] = __uint_as_float((unsigned)(w3 >> 32));
    }
    __syncthreads();             // SYNC 8: fk relay complete
    {
      const float4* v4 = (const float4*)(pool + kc * 1024);
      const float4* w4 = (const float4*)wD;                   // own slot (drained)
      float acc = 0.f;
#pragma unroll
      for (int pc = 0; pc < 4; ++pc)
        acc += dot4(w4[lane + pc * 64], v4[lane + pc * 64]);
      acc = warp_sum(acc);
      if (lane == 0) s_part[wid] = acc;
    }
    __syncthreads();             // SYNC 9
    if (tid < 4) {
      float dsum = s_part[tid * 4] + s_part[tid * 4 + 1] +
                   s_part[tid * 4 + 2] + s_part[tid * 4 + 3];
      float frs  = s_part2[tid * 4] + s_part2[tid * 4 + 1] +
                   s_part2[tid * 4 + 2] + s_part2[tid * 4 + 3];
      float fr = 1.f / (1.f + expf(-frs));
      stg_tag(&tx[((l + 1) & 1) * E + bid * 4 + tid],
              s_sx[bid * 4 + tid] + fr * dsum, tg);
    }
  }

  // ================ Head: LN_out + V x E matvec (4-way rows) ================
  {
    float xv_ = poll_tag(&tx[(NLAYER & 1) * E + tid], (unsigned)NLAYER);
    float2 mv = ln_stats(xv_, s_red);
    pool[tid] = (xv_ - mv.x) / sqrtf(mv.y + LN_EPS) * p.lnow[tid] + p.lnob[tid];
  }
  __syncthreads();
  {
    const int gw = bid * 16 + wid;
    const float4* v4 = (const float4*)pool;
    float4 x0 = v4[lane], x1 = v4[lane + 64], x2 = v4[lane + 128], x3 = v4[lane + 192];
    int row = gw;
    for (; row + 12288 < V; row += 16384) {
      const float4* W0 = (const float4*)(p.headw + (size_t)row * E);
      const float4* W1 = (const float4*)(p.headw + (size_t)(row + 4096) * E);
      const float4* W2 = (const float4*)(p.headw + (size_t)(row + 8192) * E);
      const float4* W3 = (const float4*)(p.headw + (size_t)(row + 12288) * E);
      float a0 = 0.f, a1 = 0.f, a2 = 0.f, a3 = 0.f;
      a0 += dot4(W0[lane], x0) + dot4(W0[lane + 64], x1) + dot4(W0[lane + 128], x2) + dot4(W0[lane + 192], x3);
      a1 += dot4(W1[lane], x0) + dot4(W1[lane + 64], x1) + dot4(W1[lane + 128], x2) + dot4(W1[lane + 192], x3);
      a2 += dot4(W2[lane], x0) + dot4(W2[lane + 64], x1) + dot4(W2[lane + 128], x2) + dot4(W2[lane + 192], x3);
      a3 += dot4(W3[lane], x0) + dot4(W3[lane + 64], x1) + dot4(W3[lane + 128], x2) + dot4(W3[lane + 192], x3);
      a0 = warp_sum(a0); a1 = warp_sum(a1); a2 = warp_sum(a2); a3 = warp_sum(a3);
      if (lane == 0) {
        p.out[row] = a0; p.out[row + 4096] = a1;
        p.out[row + 8192] = a2; p.out[row + 12288] = a3;
      }
    }
    for (; row < V; row += 4096) {
      const float4* W0 = (const float4*)(p.headw + (size_t)row * E);
      float a0 = dot4(W0[lane], x0) + dot4(W0[lane + 64], x1) +
                 dot4(W0[lane + 128], x2) + dot4(W0[lane + 192], x3);
      a0 = warp_sum(a0);
      if (lane == 0) p.out[row] = a0;
    }
  }
}

extern "C" void kernel_launch(void* const* d_in, const int* in_sizes, int n_in,
                              void* d_out, int out_size, void* d_ws, size_t ws_size,
                              hipStream_t stream) {
  Params p;
  p.emb   = (const float*)d_in[0];
  p.ln0_w = (const float*)d_in[1];
  p.ln0_b = (const float*)d_in[2];
  p.ln1_w = (const float*)d_in[3];
  p.ln1_b = (const float*)d_in[4];
  p.tmk   = (const float*)d_in[5];
  p.tmv   = (const float*)d_in[6];
  p.tmr   = (const float*)d_in[7];
  p.tf    = (const float*)d_in[8];
  p.td    = (const float*)d_in[9];
  p.kw    = (const float*)d_in[10];
  p.vw    = (const float*)d_in[11];
  p.rw    = (const float*)d_in[12];
  p.ow    = (const float*)d_in[13];
  p.ln2_w = (const float*)d_in[14];
  p.ln2_b = (const float*)d_in[15];
  p.ftmk  = (const float*)d_in[16];
  p.ftmr  = (const float*)d_in[17];
  p.fkw   = (const float*)d_in[18];
  p.fvw   = (const float*)d_in[19];
  p.frw   = (const float*)d_in[20];
  p.lnow  = (const float*)d_in[21];
  p.lnob  = (const float*)d_in[22];
  p.headw = (const float*)d_in[23];
  if (in_sizes[24] == 1) {
    p.tok = (const int*)d_in[24];
    p.st  = (const float*)d_in[25];
  } else {
    p.st  = (const float*)d_in[24];
    p.tok = (const int*)d_in[25];
  }
  p.out   = (float*)d_out;
  p.ws    = (float*)d_ws;

  // zero ALL tag words each launch (graph node): (10E + 2H) u64 = 147456 B
  hipMemsetAsync(d_ws, 0, (10 * E + 2 * H) * sizeof(unsigned long long), stream);

  void* args[] = { &p };
  hipLaunchCooperativeKernel((const void*)rwkv_kernel, dim3(NB), dim3(NT),
                             args, SMEMF * sizeof(float), stream);
}